// Round 12
// baseline (236.173 us; speedup 1.0000x reference)
//
#include <hip/hip_runtime.h>
#include <hip/hip_bf16.h>
#include <math.h>

#define N_NODESC 50000
#define N_EDGESC 500000
#define E_TOT    (N_EDGESC + N_NODESC)   // 550000 (self-loops appended)
#define IN_CH 128
#define HID 32
#define HEADS 4
#define HC (HEADS*HID)    // 128
#define OUT_CH 64
#define NEG_SLOPE 0.2f
#define NB_SCAN 196        // ceil(50000/256)
#define N_STRIPS (N_NODESC/16)   // 3125 exact
#define NB_HIST 2149       // ceil(E_TOT/256)
#define NB_PREP 24
#define NB_GEMM1 782       // ceil(N_STRIPS/4)

typedef unsigned short u16;
typedef __attribute__((ext_vector_type(8))) short short8;          // 8 bf16 (4 VGPRs)
typedef __attribute__((ext_vector_type(8))) unsigned short ushort8v;
typedef __attribute__((ext_vector_type(4))) float floatx4;         // 4 fp32 acc

// manual bf16 round-to-nearest-even
__device__ __forceinline__ u16 f2bf(float f){
  unsigned u = __float_as_uint(f);
  return (u16)((u + 0x7FFFu + ((u >> 16) & 1u)) >> 16);
}
__device__ __forceinline__ float bf2f(u16 b){ return __uint_as_float(((unsigned)b) << 16); }
// lrelu(v) = max(v, 0.2v)  (valid since 0 < slope < 1)
__device__ __forceinline__ float lrelu(float v){ return fmaxf(v, NEG_SLOPE*v); }

__device__ __forceinline__ void edge_sd(const int* __restrict__ ei, int e, int& s, int& d){
  if (e < N_EDGESC){ s = ei[e]; d = ei[N_EDGESC + e]; }
  else { s = e - N_EDGESC; d = s; }
}

// ---------------- misc: hist + weight prep (deg pre-zeroed by memset) ----------
__global__ void k_misc(const int* __restrict__ ei, int* __restrict__ deg,
                       const float* __restrict__ W1l, const float* __restrict__ W1r,
                       const float* __restrict__ W2l, const float* __restrict__ W2r,
                       u16* __restrict__ w1lh, u16* __restrict__ w1rh,
                       u16* __restrict__ w2lh, u16* __restrict__ w2rh){
  int b = blockIdx.x;
  if (b < NB_HIST){
    int e = b*256 + threadIdx.x;
    if (e < E_TOT){
      int s, d; edge_sd(ei, e, s, d);
      atomicAdd(&deg[d], 1);
    }
  } else {
    int bb = b - NB_HIST;
    const float* W; u16 *Th; int N, base;
    if (bb < 8)      { W=W1l; Th=w1lh; N=HC;     base=bb;    }
    else if (bb < 16){ W=W1r; Th=w1rh; N=HC;     base=bb-8;  }
    else if (bb < 20){ W=W2l; Th=w2lh; N=OUT_CH; base=bb-16; }
    else             { W=W2r; Th=w2rh; N=OUT_CH; base=bb-20; }
    // packed idx = (((c*4 + t)*64) + lane)*8 + j
    // value      = W[(t*32 + (lane>>4)*8 + j)*N + c*16 + (lane&15)]
    int tid = base*256 + threadIdx.x;
    int lane = tid & 63;
    int t = (tid >> 6) & 3;
    int c = tid >> 8;
    int k0 = t*32 + (lane>>4)*8;
    int n  = c*16 + (lane&15);
    #pragma unroll
    for (int j=0;j<8;j++){
      Th[(size_t)tid*8 + j] = f2bf(W[(size_t)(k0+j)*N + n]);
    }
  }
}

// ---------------- CSR scan ----------------
__global__ void k_scan_a(const int* __restrict__ deg, int* __restrict__ rs,
                         int* __restrict__ bsum){
  __shared__ int sh[256];
  int i = blockIdx.x*256 + threadIdx.x;
  int v = (i < N_NODESC) ? deg[i] : 0;
  sh[threadIdx.x] = v;
  __syncthreads();
  for (int off=1; off<256; off<<=1){
    int t = (threadIdx.x >= off) ? sh[threadIdx.x-off] : 0;
    __syncthreads();
    sh[threadIdx.x] += t;
    __syncthreads();
  }
  if (i < N_NODESC) rs[i] = sh[threadIdx.x] - v;       // exclusive within block
  if (threadIdx.x == 255) bsum[blockIdx.x] = sh[255];  // block total
}

// scan of bsum (redone per block, cheap) + add + cursor init
__global__ void k_scan_bc(int* __restrict__ rs, const int* __restrict__ bsum,
                          int* __restrict__ cursor){
  __shared__ int sh[256];
  int v = (threadIdx.x < NB_SCAN) ? bsum[threadIdx.x] : 0;
  sh[threadIdx.x] = v;
  __syncthreads();
  for (int off=1; off<256; off<<=1){
    int t = (threadIdx.x >= off) ? sh[threadIdx.x-off] : 0;
    __syncthreads();
    sh[threadIdx.x] += t;
    __syncthreads();
  }
  int add = sh[blockIdx.x] - bsum[blockIdx.x];
  int i = blockIdx.x*256 + threadIdx.x;
  if (i < N_NODESC){
    int v2 = rs[i] + add;
    rs[i] = v2;
    cursor[i] = v2;
  }
}

// ---------------- fill + layer-1 GEMM, merged (independent work overlapped) -------
// blocks 0..NB_HIST-1: CSR fill. blocks NB_HIST..: register-B MFMA GEMM with
// fp32 A converted to bf16 in-register (no staging pass). Waves 0,1 -> A@W1l
// into Olb; waves 2,3 -> A@W1r into Orb. NCW=4 column-tiles per wave in VGPRs.
__launch_bounds__(256, 2)
__global__ void k_fill_gemm1(const int* __restrict__ ei, int* __restrict__ cursor,
                             int* __restrict__ csrc, const float* __restrict__ X,
                             const u16* __restrict__ BlT, const u16* __restrict__ BrT,
                             u16* __restrict__ Olb, u16* __restrict__ Orb){
  int b = blockIdx.x;
  if (b < NB_HIST){
    int e = b*256 + threadIdx.x;
    if (e < E_TOT){
      int s, d; edge_sd(ei, e, s, d);
      int pos = atomicAdd(&cursor[d], 1);
      csrc[pos] = s;
    }
    return;
  }
  constexpr int NCW = 4, SPB = 4, NLD = 128;
  int wave = threadIdx.x >> 6, lane = threadIdx.x & 63;
  int m = lane & 15, quad = lane >> 4;
  bool isl = (wave < 2);
  int ctbase = (isl ? wave : wave - 2) * NCW;
  const u16* __restrict__ BT = isl ? BlT : BrT;
  u16* __restrict__ Ob = isl ? Olb : Orb;

  short8 breg[NCW][4];
  #pragma unroll
  for (int c=0;c<NCW;c++)
    #pragma unroll
    for (int t=0;t<4;t++)
      breg[c][t] = *(const short8*)(BT + ((size_t)(((ctbase+c)*4 + t)*64) + lane)*8);

  int strip0 = (b - NB_HIST) * SPB;
  short8 ah[2][4];

  auto loadA = [&](int strip, int buf){
    const float* p = X + (size_t)(strip*16 + m)*128 + quad*8;
    #pragma unroll
    for (int t=0;t<4;t++){
      float4 f0 = *(const float4*)(p + t*32);
      float4 f1 = *(const float4*)(p + t*32 + 4);
      short8 a;
      a[0]=f2bf(f0.x); a[1]=f2bf(f0.y); a[2]=f2bf(f0.z); a[3]=f2bf(f0.w);
      a[4]=f2bf(f1.x); a[5]=f2bf(f1.y); a[6]=f2bf(f1.z); a[7]=f2bf(f1.w);
      ah[buf][t] = a;
    }
  };

  loadA(strip0, 0);

  #pragma unroll
  for (int i=0;i<SPB;i++){
    int s = strip0 + i;
    if (s >= N_STRIPS) break;
    if (i+1 < SPB && s+1 < N_STRIPS) loadA(s+1, (i+1)&1);
    const int bb = i&1;
    floatx4 acc[NCW];
    #pragma unroll
    for (int c=0;c<NCW;c++) acc[c] = (floatx4){0.f,0.f,0.f,0.f};
    #pragma unroll
    for (int t=0;t<4;t++){
      #pragma unroll
      for (int c=0;c<NCW;c++)
        acc[c] = __builtin_amdgcn_mfma_f32_16x16x32_bf16(ah[bb][t], breg[c][t], acc[c], 0,0,0);
    }
    int row0 = s*16;
    #pragma unroll
    for (int c=0;c<NCW;c++)
      #pragma unroll
      for (int r=0;r<4;r++)
        Ob[(size_t)(row0 + quad*4 + r)*NLD + (ctbase+c)*16 + m] = f2bf(acc[c][r]);
  }
}

// ---------------- layer-2 GEMM (bf16 A from fused1) ----------------
template<int NCW, int SPB>
__launch_bounds__(256, 2)
__global__ void k_gemm_regB(const u16* __restrict__ Ab,
                            const u16* __restrict__ BlT, const u16* __restrict__ BrT,
                            u16* __restrict__ Olb, u16* __restrict__ Orb){
  constexpr int NLD = 2*NCW*16;
  int wave = threadIdx.x >> 6, lane = threadIdx.x & 63;
  int m = lane & 15, quad = lane >> 4;
  bool isl = (wave < 2);
  int ctbase = (isl ? wave : wave - 2) * NCW;
  const u16* __restrict__ BT = isl ? BlT : BrT;
  u16* __restrict__ Ob = isl ? Olb : Orb;

  short8 breg[NCW][4];
  #pragma unroll
  for (int c=0;c<NCW;c++)
    #pragma unroll
    for (int t=0;t<4;t++)
      breg[c][t] = *(const short8*)(BT + ((size_t)(((ctbase+c)*4 + t)*64) + lane)*8);

  int strip0 = blockIdx.x * SPB;
  short8 ah[2][4];

  {
    const u16* p1 = Ab + (size_t)(strip0*16 + m)*128 + quad*8;
    #pragma unroll
    for (int t=0;t<4;t++) ah[0][t] = *(const short8*)(p1 + t*32);
  }

  #pragma unroll
  for (int i=0;i<SPB;i++){
    int s = strip0 + i;
    if (s >= N_STRIPS) break;
    if (i+1 < SPB && s+1 < N_STRIPS){
      const u16* p1 = Ab + (size_t)((s+1)*16 + m)*128 + quad*8;
      #pragma unroll
      for (int t=0;t<4;t++) ah[(i+1)&1][t] = *(const short8*)(p1 + t*32);
    }
    const int b = i&1;
    floatx4 acc[NCW];
    #pragma unroll
    for (int c=0;c<NCW;c++) acc[c] = (floatx4){0.f,0.f,0.f,0.f};
    #pragma unroll
    for (int t=0;t<4;t++){
      #pragma unroll
      for (int c=0;c<NCW;c++)
        acc[c] = __builtin_amdgcn_mfma_f32_16x16x32_bf16(ah[b][t], breg[c][t], acc[c], 0,0,0);
    }
    int row0 = s*16;
    #pragma unroll
    for (int c=0;c<NCW;c++)
      #pragma unroll
      for (int r=0;r<4;r++)
        Ob[(size_t)(row0 + quad*4 + r)*NLD + (ctbase+c)*16 + m] = f2bf(acc[c][r]);
  }
}

// ---------------- layer 1 fused: 4 groups x 16 lanes, MLP=2 ----------------
// Wave per dst. 64 indices per coalesced load, broadcast via __shfl. Per inner
// iteration each group issues TWO independent 16B gathers (edges i+g, i+4+g)
// then consumes both. No max-subtraction (scores O(5); alpha shift-invariant).
__global__ void k_fused1(const int* __restrict__ rs, const int* __restrict__ deg,
                         const int* __restrict__ csrc, const u16* __restrict__ xlb,
                         const u16* __restrict__ xrb, const float* __restrict__ att,
                         const float* __restrict__ b1, u16* __restrict__ Hb){
  int wave = threadIdx.x >> 6;
  int lane = threadIdx.x & 63;
  int d = blockIdx.x*4 + wave;
  if (d >= N_NODESC) return;
  int g = lane >> 4;        // edge-slot group
  int l = lane & 15;        // channel slice: 8l..8l+7

  float xrv[8], atv[8];
  {
    ushort8v xq = *(const ushort8v*)(xrb + (size_t)d*HC + 8*l);
    #pragma unroll
    for (int j=0;j<8;j++) xrv[j] = bf2f(xq[j]);
    float4 c = *(const float4*)(att + 8*l);
    float4 e = *(const float4*)(att + 8*l + 4);
    atv[0]=c.x; atv[1]=c.y; atv[2]=c.z; atv[3]=c.w;
    atv[4]=e.x; atv[5]=e.y; atv[6]=e.z; atv[7]=e.w;
  }

  int start = rs[d], degd = deg[d];

  float acc[8];
  #pragma unroll
  for (int j=0;j<8;j++) acc[j] = 0.f;
  float den = 0.f;

  for (int base = 0; base < degd; base += 64){
    int nb = degd - base; if (nb > 64) nb = 64;
    int idx = csrc[start + base + ((lane < nb) ? lane : 0)];   // one coalesced load
    for (int i = 0; i < nb; i += 8){
      int e0 = i + g, e1 = i + 4 + g;          // both <= 63
      bool v0 = (e0 < nb), v1 = (e1 < nb);
      int s0 = __shfl(idx, e0);
      int s1 = __shfl(idx, e1);
      ushort8v q0 = *(const ushort8v*)(xlb + (size_t)s0*HC + 8*l);  // 16B gather
      ushort8v q1 = *(const ushort8v*)(xlb + (size_t)s1*HC + 8*l);  // 16B gather
      {
        float xv[8]; float sc = 0.f;
        #pragma unroll
        for (int j=0;j<8;j++){ xv[j] = bf2f(q0[j]); sc = fmaf(lrelu(xv[j]+xrv[j]), atv[j], sc); }
        sc += __shfl_xor(sc, 1);
        sc += __shfl_xor(sc, 2);              // per-head sum (4-lane span)
        float p = v0 ? __expf(sc) : 0.f;
        den += p;
        #pragma unroll
        for (int j=0;j<8;j++) acc[j] = fmaf(p, xv[j], acc[j]);
      }
      {
        float xv[8]; float sc = 0.f;
        #pragma unroll
        for (int j=0;j<8;j++){ xv[j] = bf2f(q1[j]); sc = fmaf(lrelu(xv[j]+xrv[j]), atv[j], sc); }
        sc += __shfl_xor(sc, 1);
        sc += __shfl_xor(sc, 2);
        float p = v1 ? __expf(sc) : 0.f;
        den += p;
        #pragma unroll
        for (int j=0;j<8;j++) acc[j] = fmaf(p, xv[j], acc[j]);
      }
    }
  }
  // cross-group combine
  #pragma unroll
  for (int j=0;j<8;j++){
    acc[j] += __shfl_xor(acc[j], 16);
    acc[j] += __shfl_xor(acc[j], 32);
  }
  den += __shfl_xor(den, 16);
  den += __shfl_xor(den, 32);

  if (g == 0){
    float bv[8];
    float4 a = *(const float4*)(b1 + 8*l);
    float4 b = *(const float4*)(b1 + 8*l + 4);
    bv[0]=a.x; bv[1]=a.y; bv[2]=a.z; bv[3]=a.w;
    bv[4]=b.x; bv[5]=b.y; bv[6]=b.z; bv[7]=b.w;
    float inv = 1.f / (den + 1e-16f);
    u16 ohv[8];
    #pragma unroll
    for (int j=0;j<8;j++){
      float o = acc[j]*inv + bv[j];
      o = (o > 0.f) ? o : (__expf(o) - 1.f);
      ohv[j] = f2bf(o);
    }
    ushort4 h0 = {ohv[0],ohv[1],ohv[2],ohv[3]}, h1 = {ohv[4],ohv[5],ohv[6],ohv[7]};
    *(ushort4*)(Hb + (size_t)d*HC + 8*l)     = h0;
    *(ushort4*)(Hb + (size_t)d*HC + 8*l + 4) = h1;
  }
}

// ---------------- layer 2 fused: 8 groups x 8 lanes, MLP=2 ----------------
// Lane l covers ch 8l..8l+7 (16B gather); score over 8 lanes (3 shfl); heads=1.
__global__ void k_fused2(const int* __restrict__ rs, const int* __restrict__ deg,
                         const int* __restrict__ csrc, const u16* __restrict__ xlb,
                         const u16* __restrict__ xrb, const float* __restrict__ att,
                         const float* __restrict__ b2, float* __restrict__ out){
  int wave = threadIdx.x >> 6;
  int lane = threadIdx.x & 63;
  int d = blockIdx.x*4 + wave;
  if (d >= N_NODESC) return;
  int g = lane >> 3;        // 8 edge slots
  int l = lane & 7;         // channels 8l..8l+7

  float xrv[8], atv[8];
  {
    ushort8v xq = *(const ushort8v*)(xrb + (size_t)d*OUT_CH + 8*l);
    #pragma unroll
    for (int j=0;j<8;j++) xrv[j] = bf2f(xq[j]);
    float4 c = *(const float4*)(att + 8*l);
    float4 e = *(const float4*)(att + 8*l + 4);
    atv[0]=c.x; atv[1]=c.y; atv[2]=c.z; atv[3]=c.w;
    atv[4]=e.x; atv[5]=e.y; atv[6]=e.z; atv[7]=e.w;
  }

  int start = rs[d], degd = deg[d];

  float acc[8];
  #pragma unroll
  for (int j=0;j<8;j++) acc[j] = 0.f;
  float den = 0.f;

  for (int base = 0; base < degd; base += 64){
    int nb = degd - base; if (nb > 64) nb = 64;
    int idx = csrc[start + base + ((lane < nb) ? lane : 0)];
    for (int i = 0; i < nb; i += 16){
      int e0 = i + g, e1 = i + 8 + g;          // both <= 63
      bool v0 = (e0 < nb), v1 = (e1 < nb);
      int s0 = __shfl(idx, e0);
      int s1 = __shfl(idx, e1);
      ushort8v q0 = *(const ushort8v*)(xlb + (size_t)s0*OUT_CH + 8*l);  // 16B gather
      ushort8v q1 = *(const ushort8v*)(xlb + (size_t)s1*OUT_CH + 8*l);  // 16B gather
      {
        float xv[8]; float sc = 0.f;
        #pragma unroll
        for (int j=0;j<8;j++){ xv[j] = bf2f(q0[j]); sc = fmaf(lrelu(xv[j]+xrv[j]), atv[j], sc); }
        sc += __shfl_xor(sc, 1);
        sc += __shfl_xor(sc, 2);
        sc += __shfl_xor(sc, 4);              // full 64-ch sum (8-lane span)
        float p = v0 ? __expf(sc) : 0.f;
        den += p;
        #pragma unroll
        for (int j=0;j<8;j++) acc[j] = fmaf(p, xv[j], acc[j]);
      }
      {
        float xv[8]; float sc = 0.f;
        #pragma unroll
        for (int j=0;j<8;j++){ xv[j] = bf2f(q1[j]); sc = fmaf(lrelu(xv[j]+xrv[j]), atv[j], sc); }
        sc += __shfl_xor(sc, 1);
        sc += __shfl_xor(sc, 2);
        sc += __shfl_xor(sc, 4);
        float p = v1 ? __expf(sc) : 0.f;
        den += p;
        #pragma unroll
        for (int j=0;j<8;j++) acc[j] = fmaf(p, xv[j], acc[j]);
      }
    }
  }
  // cross-group combine (8 groups)
  #pragma unroll
  for (int j=0;j<8;j++){
    acc[j] += __shfl_xor(acc[j], 8);
    acc[j] += __shfl_xor(acc[j], 16);
    acc[j] += __shfl_xor(acc[j], 32);
  }
  den += __shfl_xor(den, 8);
  den += __shfl_xor(den, 16);
  den += __shfl_xor(den, 32);

  if (g == 0){
    float bv[8];
    float4 a = *(const float4*)(b2 + 8*l);
    float4 b = *(const float4*)(b2 + 8*l + 4);
    bv[0]=a.x; bv[1]=a.y; bv[2]=a.z; bv[3]=a.w;
    bv[4]=b.x; bv[5]=b.y; bv[6]=b.z; bv[7]=b.w;
    float inv = 1.f / (den + 1e-16f);
    float4 o0, o1;
    o0.x = acc[0]*inv + bv[0]; o0.y = acc[1]*inv + bv[1];
    o0.z = acc[2]*inv + bv[2]; o0.w = acc[3]*inv + bv[3];
    o1.x = acc[4]*inv + bv[4]; o1.y = acc[5]*inv + bv[5];
    o1.z = acc[6]*inv + bv[6]; o1.w = acc[7]*inv + bv[7];
    *(float4*)(out + (size_t)d*OUT_CH + 8*l)     = o0;
    *(float4*)(out + (size_t)d*OUT_CH + 8*l + 4) = o1;
  }
}

extern "C" void kernel_launch(void* const* d_in, const int* in_sizes, int n_in,
                              void* d_out, int out_size, void* d_ws, size_t ws_size,
                              hipStream_t stream) {
  const float* x    = (const float*)d_in[0];
  const int*   ei   = (const int*)d_in[1];
  const float* W1l  = (const float*)d_in[2];
  const float* W1r  = (const float*)d_in[3];
  const float* att1 = (const float*)d_in[4];
  const float* b1   = (const float*)d_in[5];
  const float* W2l  = (const float*)d_in[6];
  const float* W2r  = (const float*)d_in[7];
  const float* att2 = (const float*)d_in[8];
  const float* b2   = (const float*)d_in[9];
  float* out = (float*)d_out;

  // workspace layout (units of float; offsets multiples of 4 -> 16B aligned)
  float* ws = (float*)d_ws;
  size_t off = 0;
  u16* xl1b = (u16*)(ws + off); off += (size_t)N_NODESC*HC/2;     // bf16 [N x 128]
  u16* xr1b = (u16*)(ws + off); off += (size_t)N_NODESC*HC/2;
  u16* xl2b = (u16*)(ws + off); off += (size_t)N_NODESC*OUT_CH/2; // bf16 [N x 64]
  u16* xr2b = (u16*)(ws + off); off += (size_t)N_NODESC*OUT_CH/2;
  u16* hb   = (u16*)(ws + off); off += (size_t)N_NODESC*HC/2;     // bf16 A for gemm2
  u16* w1lh = (u16*)(ws + off); off += IN_CH*HC/2;
  u16* w1rh = (u16*)(ws + off); off += IN_CH*HC/2;
  u16* w2lh = (u16*)(ws + off); off += HC*OUT_CH/2;
  u16* w2rh = (u16*)(ws + off); off += HC*OUT_CH/2;
  int* deg    = (int*)(ws + off); off += N_NODESC;
  int* rs     = (int*)(ws + off); off += N_NODESC;
  int* cursor = (int*)(ws + off); off += N_NODESC;
  int* bsum   = (int*)(ws + off); off += 256;
  int* csrc   = (int*)(ws + off); off += E_TOT;

  // ---- zero deg + misc (hist + weight prep) + CSR scan ----
  hipMemsetAsync(deg, 0, N_NODESC*sizeof(int), stream);
  k_misc<<<NB_HIST + NB_PREP, 256, 0, stream>>>(
      ei, deg, W1l, W1r, W2l, W2r, w1lh, w1rh, w2lh, w2rh);
  k_scan_a<<<NB_SCAN, 256, 0, stream>>>(deg, rs, bsum);
  k_scan_bc<<<NB_SCAN, 256, 0, stream>>>(rs, bsum, cursor);

  // ---- fill + layer-1 GEMM merged (independent, overlapped) ----
  k_fill_gemm1<<<NB_HIST + NB_GEMM1, 256, 0, stream>>>(
      ei, cursor, csrc, x, w1lh, w1rh, xl1b, xr1b);

  // ---- layer 1 aggregate ----
  k_fused1<<<(N_NODESC+3)/4, 256, 0, stream>>>(rs, deg, csrc, xl1b, xr1b, att1, b1, hb);

  // ---- layer 2 ----
  k_gemm_regB<2,4><<<(N_STRIPS+3)/4, 256, 0, stream>>>(hb, w2lh, w2rh, xl2b, xr2b);
  k_fused2<<<(N_NODESC+3)/4, 256, 0, stream>>>(rs, deg, csrc, xl2b, xr2b, att2, b2, out);
}

// Round 13
// 235.997 us; speedup vs baseline: 1.0007x; 1.0007x over previous
//
#include <hip/hip_runtime.h>
#include <hip/hip_bf16.h>
#include <math.h>

#define N_NODESC 50000
#define N_EDGESC 500000
#define E_TOT    (N_EDGESC + N_NODESC)   // 550000 (self-loops appended)
#define IN_CH 128
#define HID 32
#define HEADS 4
#define HC (HEADS*HID)    // 128
#define OUT_CH 64
#define NEG_SLOPE 0.2f
#define NB_SCAN 196        // ceil(50000/256)
#define N_STRIPS (N_NODESC/16)   // 3125 exact
#define NB_HIST 2149       // ceil(E_TOT/256)
#define NB_PREP 24

typedef unsigned short u16;
typedef __attribute__((ext_vector_type(8))) short short8;          // 8 bf16 (4 VGPRs)
typedef __attribute__((ext_vector_type(8))) unsigned short ushort8v;
typedef __attribute__((ext_vector_type(4))) float floatx4;         // 4 fp32 acc

// manual bf16 round-to-nearest-even
__device__ __forceinline__ u16 f2bf(float f){
  unsigned u = __float_as_uint(f);
  return (u16)((u + 0x7FFFu + ((u >> 16) & 1u)) >> 16);
}
__device__ __forceinline__ float bf2f(u16 b){ return __uint_as_float(((unsigned)b) << 16); }
// lrelu(v) = max(v, 0.2v)  (valid since 0 < slope < 1)
__device__ __forceinline__ float lrelu(float v){ return fmaxf(v, NEG_SLOPE*v); }

__device__ __forceinline__ void edge_sd(const int* __restrict__ ei, int e, int& s, int& d){
  if (e < N_EDGESC){ s = ei[e]; d = ei[N_EDGESC + e]; }
  else { s = e - N_EDGESC; d = s; }
}

// ---------------- misc: hist + weight prep (deg pre-zeroed by memset) ----------
__global__ void k_misc(const int* __restrict__ ei, int* __restrict__ deg,
                       const float* __restrict__ W1l, const float* __restrict__ W1r,
                       const float* __restrict__ W2l, const float* __restrict__ W2r,
                       u16* __restrict__ w1lh, u16* __restrict__ w1rh,
                       u16* __restrict__ w2lh, u16* __restrict__ w2rh){
  int b = blockIdx.x;
  if (b < NB_HIST){
    int e = b*256 + threadIdx.x;
    if (e < E_TOT){
      int s, d; edge_sd(ei, e, s, d);
      atomicAdd(&deg[d], 1);
    }
  } else {
    int bb = b - NB_HIST;
    const float* W; u16 *Th; int N, base;
    if (bb < 8)      { W=W1l; Th=w1lh; N=HC;     base=bb;    }
    else if (bb < 16){ W=W1r; Th=w1rh; N=HC;     base=bb-8;  }
    else if (bb < 20){ W=W2l; Th=w2lh; N=OUT_CH; base=bb-16; }
    else             { W=W2r; Th=w2rh; N=OUT_CH; base=bb-20; }
    // packed idx = (((c*4 + t)*64) + lane)*8 + j
    // value      = W[(t*32 + (lane>>4)*8 + j)*N + c*16 + (lane&15)]
    int tid = base*256 + threadIdx.x;
    int lane = tid & 63;
    int t = (tid >> 6) & 3;
    int c = tid >> 8;
    int k0 = t*32 + (lane>>4)*8;
    int n  = c*16 + (lane&15);
    #pragma unroll
    for (int j=0;j<8;j++){
      Th[(size_t)tid*8 + j] = f2bf(W[(size_t)(k0+j)*N + n]);
    }
  }
}

// ---------------- CSR scan ----------------
__global__ void k_scan_a(const int* __restrict__ deg, int* __restrict__ rs,
                         int* __restrict__ bsum){
  __shared__ int sh[256];
  int i = blockIdx.x*256 + threadIdx.x;
  int v = (i < N_NODESC) ? deg[i] : 0;
  sh[threadIdx.x] = v;
  __syncthreads();
  for (int off=1; off<256; off<<=1){
    int t = (threadIdx.x >= off) ? sh[threadIdx.x-off] : 0;
    __syncthreads();
    sh[threadIdx.x] += t;
    __syncthreads();
  }
  if (i < N_NODESC) rs[i] = sh[threadIdx.x] - v;       // exclusive within block
  if (threadIdx.x == 255) bsum[blockIdx.x] = sh[255];  // block total
}

// scan of bsum (redone per block, cheap) + add + cursor init
__global__ void k_scan_bc(int* __restrict__ rs, const int* __restrict__ bsum,
                          int* __restrict__ cursor){
  __shared__ int sh[256];
  int v = (threadIdx.x < NB_SCAN) ? bsum[threadIdx.x] : 0;
  sh[threadIdx.x] = v;
  __syncthreads();
  for (int off=1; off<256; off<<=1){
    int t = (threadIdx.x >= off) ? sh[threadIdx.x-off] : 0;
    __syncthreads();
    sh[threadIdx.x] += t;
    __syncthreads();
  }
  int add = sh[blockIdx.x] - bsum[blockIdx.x];
  int i = blockIdx.x*256 + threadIdx.x;
  if (i < N_NODESC){
    int v2 = rs[i] + add;
    rs[i] = v2;
    cursor[i] = v2;
  }
}

// ---------------- CSR fill (lightweight, high occupancy) ----------------
__global__ void k_fill(const int* __restrict__ ei, int* __restrict__ cursor,
                       int* __restrict__ csrc){
  int e = blockIdx.x*blockDim.x + threadIdx.x;
  if (e >= E_TOT) return;
  int s, d; edge_sd(ei, e, s, d);
  int pos = atomicAdd(&cursor[d], 1);
  csrc[pos] = s;
}

// ---------------- layer-1 GEMM: fp32 A converted to bf16 in-register ------------
// Block = 4 waves. Waves 0,1 -> A@W1l into Olb; waves 2,3 -> A@W1r into Orb.
// NCW=4 column-tiles of B per wave in VGPRs; A double-buffered in registers.
__launch_bounds__(256, 2)
__global__ void k_gemm1(const float* __restrict__ X,
                        const u16* __restrict__ BlT, const u16* __restrict__ BrT,
                        u16* __restrict__ Olb, u16* __restrict__ Orb){
  constexpr int NCW = 4, SPB = 4, NLD = 128;
  int wave = threadIdx.x >> 6, lane = threadIdx.x & 63;
  int m = lane & 15, quad = lane >> 4;
  bool isl = (wave < 2);
  int ctbase = (isl ? wave : wave - 2) * NCW;
  const u16* __restrict__ BT = isl ? BlT : BrT;
  u16* __restrict__ Ob = isl ? Olb : Orb;

  short8 breg[NCW][4];
  #pragma unroll
  for (int c=0;c<NCW;c++)
    #pragma unroll
    for (int t=0;t<4;t++)
      breg[c][t] = *(const short8*)(BT + ((size_t)(((ctbase+c)*4 + t)*64) + lane)*8);

  int strip0 = blockIdx.x * SPB;
  short8 ah[2][4];

  auto loadA = [&](int strip, int buf){
    const float* p = X + (size_t)(strip*16 + m)*128 + quad*8;
    #pragma unroll
    for (int t=0;t<4;t++){
      float4 f0 = *(const float4*)(p + t*32);
      float4 f1 = *(const float4*)(p + t*32 + 4);
      short8 a;
      a[0]=f2bf(f0.x); a[1]=f2bf(f0.y); a[2]=f2bf(f0.z); a[3]=f2bf(f0.w);
      a[4]=f2bf(f1.x); a[5]=f2bf(f1.y); a[6]=f2bf(f1.z); a[7]=f2bf(f1.w);
      ah[buf][t] = a;
    }
  };

  loadA(strip0, 0);

  #pragma unroll
  for (int i=0;i<SPB;i++){
    int s = strip0 + i;
    if (s >= N_STRIPS) break;
    if (i+1 < SPB && s+1 < N_STRIPS) loadA(s+1, (i+1)&1);
    const int bb = i&1;
    floatx4 acc[NCW];
    #pragma unroll
    for (int c=0;c<NCW;c++) acc[c] = (floatx4){0.f,0.f,0.f,0.f};
    #pragma unroll
    for (int t=0;t<4;t++){
      #pragma unroll
      for (int c=0;c<NCW;c++)
        acc[c] = __builtin_amdgcn_mfma_f32_16x16x32_bf16(ah[bb][t], breg[c][t], acc[c], 0,0,0);
    }
    int row0 = s*16;
    #pragma unroll
    for (int c=0;c<NCW;c++)
      #pragma unroll
      for (int r=0;r<4;r++)
        Ob[(size_t)(row0 + quad*4 + r)*NLD + (ctbase+c)*16 + m] = f2bf(acc[c][r]);
  }
}

// ---------------- layer-2 GEMM (bf16 A from fused1) ----------------
template<int NCW, int SPB>
__launch_bounds__(256, 2)
__global__ void k_gemm_regB(const u16* __restrict__ Ab,
                            const u16* __restrict__ BlT, const u16* __restrict__ BrT,
                            u16* __restrict__ Olb, u16* __restrict__ Orb){
  constexpr int NLD = 2*NCW*16;
  int wave = threadIdx.x >> 6, lane = threadIdx.x & 63;
  int m = lane & 15, quad = lane >> 4;
  bool isl = (wave < 2);
  int ctbase = (isl ? wave : wave - 2) * NCW;
  const u16* __restrict__ BT = isl ? BlT : BrT;
  u16* __restrict__ Ob = isl ? Olb : Orb;

  short8 breg[NCW][4];
  #pragma unroll
  for (int c=0;c<NCW;c++)
    #pragma unroll
    for (int t=0;t<4;t++)
      breg[c][t] = *(const short8*)(BT + ((size_t)(((ctbase+c)*4 + t)*64) + lane)*8);

  int strip0 = blockIdx.x * SPB;
  short8 ah[2][4];

  {
    const u16* p1 = Ab + (size_t)(strip0*16 + m)*128 + quad*8;
    #pragma unroll
    for (int t=0;t<4;t++) ah[0][t] = *(const short8*)(p1 + t*32);
  }

  #pragma unroll
  for (int i=0;i<SPB;i++){
    int s = strip0 + i;
    if (s >= N_STRIPS) break;
    if (i+1 < SPB && s+1 < N_STRIPS){
      const u16* p1 = Ab + (size_t)((s+1)*16 + m)*128 + quad*8;
      #pragma unroll
      for (int t=0;t<4;t++) ah[(i+1)&1][t] = *(const short8*)(p1 + t*32);
    }
    const int b = i&1;
    floatx4 acc[NCW];
    #pragma unroll
    for (int c=0;c<NCW;c++) acc[c] = (floatx4){0.f,0.f,0.f,0.f};
    #pragma unroll
    for (int t=0;t<4;t++){
      #pragma unroll
      for (int c=0;c<NCW;c++)
        acc[c] = __builtin_amdgcn_mfma_f32_16x16x32_bf16(ah[b][t], breg[c][t], acc[c], 0,0,0);
    }
    int row0 = s*16;
    #pragma unroll
    for (int c=0;c<NCW;c++)
      #pragma unroll
      for (int r=0;r<4;r++)
        Ob[(size_t)(row0 + quad*4 + r)*NLD + (ctbase+c)*16 + m] = f2bf(acc[c][r]);
  }
}

// ---------------- layer 1 fused: 4 groups x 16 lanes, MLP=2 ----------------
// Wave per dst. 64 indices per coalesced load, broadcast via __shfl. Per inner
// iteration each group issues TWO independent 16B gathers (edges i+g, i+4+g)
// then consumes both. No max-subtraction (scores O(5); alpha shift-invariant).
__global__ void k_fused1(const int* __restrict__ rs, const int* __restrict__ deg,
                         const int* __restrict__ csrc, const u16* __restrict__ xlb,
                         const u16* __restrict__ xrb, const float* __restrict__ att,
                         const float* __restrict__ b1, u16* __restrict__ Hb){
  int wave = threadIdx.x >> 6;
  int lane = threadIdx.x & 63;
  int d = blockIdx.x*4 + wave;
  if (d >= N_NODESC) return;
  int g = lane >> 4;        // edge-slot group
  int l = lane & 15;        // channel slice: 8l..8l+7

  float xrv[8], atv[8];
  {
    ushort8v xq = *(const ushort8v*)(xrb + (size_t)d*HC + 8*l);
    #pragma unroll
    for (int j=0;j<8;j++) xrv[j] = bf2f(xq[j]);
    float4 c = *(const float4*)(att + 8*l);
    float4 e = *(const float4*)(att + 8*l + 4);
    atv[0]=c.x; atv[1]=c.y; atv[2]=c.z; atv[3]=c.w;
    atv[4]=e.x; atv[5]=e.y; atv[6]=e.z; atv[7]=e.w;
  }

  int start = rs[d], degd = deg[d];

  float acc[8];
  #pragma unroll
  for (int j=0;j<8;j++) acc[j] = 0.f;
  float den = 0.f;

  for (int base = 0; base < degd; base += 64){
    int nb = degd - base; if (nb > 64) nb = 64;
    int idx = csrc[start + base + ((lane < nb) ? lane : 0)];   // one coalesced load
    for (int i = 0; i < nb; i += 8){
      int e0 = i + g, e1 = i + 4 + g;          // both <= 63
      bool v0 = (e0 < nb), v1 = (e1 < nb);
      int s0 = __shfl(idx, e0);
      int s1 = __shfl(idx, e1);
      ushort8v q0 = *(const ushort8v*)(xlb + (size_t)s0*HC + 8*l);  // 16B gather
      ushort8v q1 = *(const ushort8v*)(xlb + (size_t)s1*HC + 8*l);  // 16B gather
      {
        float xv[8]; float sc = 0.f;
        #pragma unroll
        for (int j=0;j<8;j++){ xv[j] = bf2f(q0[j]); sc = fmaf(lrelu(xv[j]+xrv[j]), atv[j], sc); }
        sc += __shfl_xor(sc, 1);
        sc += __shfl_xor(sc, 2);              // per-head sum (4-lane span)
        float p = v0 ? __expf(sc) : 0.f;
        den += p;
        #pragma unroll
        for (int j=0;j<8;j++) acc[j] = fmaf(p, xv[j], acc[j]);
      }
      {
        float xv[8]; float sc = 0.f;
        #pragma unroll
        for (int j=0;j<8;j++){ xv[j] = bf2f(q1[j]); sc = fmaf(lrelu(xv[j]+xrv[j]), atv[j], sc); }
        sc += __shfl_xor(sc, 1);
        sc += __shfl_xor(sc, 2);
        float p = v1 ? __expf(sc) : 0.f;
        den += p;
        #pragma unroll
        for (int j=0;j<8;j++) acc[j] = fmaf(p, xv[j], acc[j]);
      }
    }
  }
  // cross-group combine
  #pragma unroll
  for (int j=0;j<8;j++){
    acc[j] += __shfl_xor(acc[j], 16);
    acc[j] += __shfl_xor(acc[j], 32);
  }
  den += __shfl_xor(den, 16);
  den += __shfl_xor(den, 32);

  if (g == 0){
    float bv[8];
    float4 a = *(const float4*)(b1 + 8*l);
    float4 b = *(const float4*)(b1 + 8*l + 4);
    bv[0]=a.x; bv[1]=a.y; bv[2]=a.z; bv[3]=a.w;
    bv[4]=b.x; bv[5]=b.y; bv[6]=b.z; bv[7]=b.w;
    float inv = 1.f / (den + 1e-16f);
    u16 ohv[8];
    #pragma unroll
    for (int j=0;j<8;j++){
      float o = acc[j]*inv + bv[j];
      o = (o > 0.f) ? o : (__expf(o) - 1.f);
      ohv[j] = f2bf(o);
    }
    ushort4 h0 = {ohv[0],ohv[1],ohv[2],ohv[3]}, h1 = {ohv[4],ohv[5],ohv[6],ohv[7]};
    *(ushort4*)(Hb + (size_t)d*HC + 8*l)     = h0;
    *(ushort4*)(Hb + (size_t)d*HC + 8*l + 4) = h1;
  }
}

// ---------------- layer 2 fused: 8 groups x 8 lanes, MLP=2 ----------------
// Lane l covers ch 8l..8l+7 (16B gather); score over 8 lanes (3 shfl); heads=1.
__global__ void k_fused2(const int* __restrict__ rs, const int* __restrict__ deg,
                         const int* __restrict__ csrc, const u16* __restrict__ xlb,
                         const u16* __restrict__ xrb, const float* __restrict__ att,
                         const float* __restrict__ b2, float* __restrict__ out){
  int wave = threadIdx.x >> 6;
  int lane = threadIdx.x & 63;
  int d = blockIdx.x*4 + wave;
  if (d >= N_NODESC) return;
  int g = lane >> 3;        // 8 edge slots
  int l = lane & 7;         // channels 8l..8l+7

  float xrv[8], atv[8];
  {
    ushort8v xq = *(const ushort8v*)(xrb + (size_t)d*OUT_CH + 8*l);
    #pragma unroll
    for (int j=0;j<8;j++) xrv[j] = bf2f(xq[j]);
    float4 c = *(const float4*)(att + 8*l);
    float4 e = *(const float4*)(att + 8*l + 4);
    atv[0]=c.x; atv[1]=c.y; atv[2]=c.z; atv[3]=c.w;
    atv[4]=e.x; atv[5]=e.y; atv[6]=e.z; atv[7]=e.w;
  }

  int start = rs[d], degd = deg[d];

  float acc[8];
  #pragma unroll
  for (int j=0;j<8;j++) acc[j] = 0.f;
  float den = 0.f;

  for (int base = 0; base < degd; base += 64){
    int nb = degd - base; if (nb > 64) nb = 64;
    int idx = csrc[start + base + ((lane < nb) ? lane : 0)];
    for (int i = 0; i < nb; i += 16){
      int e0 = i + g, e1 = i + 8 + g;          // both <= 63
      bool v0 = (e0 < nb), v1 = (e1 < nb);
      int s0 = __shfl(idx, e0);
      int s1 = __shfl(idx, e1);
      ushort8v q0 = *(const ushort8v*)(xlb + (size_t)s0*OUT_CH + 8*l);  // 16B gather
      ushort8v q1 = *(const ushort8v*)(xlb + (size_t)s1*OUT_CH + 8*l);  // 16B gather
      {
        float xv[8]; float sc = 0.f;
        #pragma unroll
        for (int j=0;j<8;j++){ xv[j] = bf2f(q0[j]); sc = fmaf(lrelu(xv[j]+xrv[j]), atv[j], sc); }
        sc += __shfl_xor(sc, 1);
        sc += __shfl_xor(sc, 2);
        sc += __shfl_xor(sc, 4);              // full 64-ch sum (8-lane span)
        float p = v0 ? __expf(sc) : 0.f;
        den += p;
        #pragma unroll
        for (int j=0;j<8;j++) acc[j] = fmaf(p, xv[j], acc[j]);
      }
      {
        float xv[8]; float sc = 0.f;
        #pragma unroll
        for (int j=0;j<8;j++){ xv[j] = bf2f(q1[j]); sc = fmaf(lrelu(xv[j]+xrv[j]), atv[j], sc); }
        sc += __shfl_xor(sc, 1);
        sc += __shfl_xor(sc, 2);
        sc += __shfl_xor(sc, 4);
        float p = v1 ? __expf(sc) : 0.f;
        den += p;
        #pragma unroll
        for (int j=0;j<8;j++) acc[j] = fmaf(p, xv[j], acc[j]);
      }
    }
  }
  // cross-group combine (8 groups)
  #pragma unroll
  for (int j=0;j<8;j++){
    acc[j] += __shfl_xor(acc[j], 8);
    acc[j] += __shfl_xor(acc[j], 16);
    acc[j] += __shfl_xor(acc[j], 32);
  }
  den += __shfl_xor(den, 8);
  den += __shfl_xor(den, 16);
  den += __shfl_xor(den, 32);

  if (g == 0){
    float bv[8];
    float4 a = *(const float4*)(b2 + 8*l);
    float4 b = *(const float4*)(b2 + 8*l + 4);
    bv[0]=a.x; bv[1]=a.y; bv[2]=a.z; bv[3]=a.w;
    bv[4]=b.x; bv[5]=b.y; bv[6]=b.z; bv[7]=b.w;
    float inv = 1.f / (den + 1e-16f);
    float4 o0, o1;
    o0.x = acc[0]*inv + bv[0]; o0.y = acc[1]*inv + bv[1];
    o0.z = acc[2]*inv + bv[2]; o0.w = acc[3]*inv + bv[3];
    o1.x = acc[4]*inv + bv[4]; o1.y = acc[5]*inv + bv[5];
    o1.z = acc[6]*inv + bv[6]; o1.w = acc[7]*inv + bv[7];
    *(float4*)(out + (size_t)d*OUT_CH + 8*l)     = o0;
    *(float4*)(out + (size_t)d*OUT_CH + 8*l + 4) = o1;
  }
}

extern "C" void kernel_launch(void* const* d_in, const int* in_sizes, int n_in,
                              void* d_out, int out_size, void* d_ws, size_t ws_size,
                              hipStream_t stream) {
  const float* x    = (const float*)d_in[0];
  const int*   ei   = (const int*)d_in[1];
  const float* W1l  = (const float*)d_in[2];
  const float* W1r  = (const float*)d_in[3];
  const float* att1 = (const float*)d_in[4];
  const float* b1   = (const float*)d_in[5];
  const float* W2l  = (const float*)d_in[6];
  const float* W2r  = (const float*)d_in[7];
  const float* att2 = (const float*)d_in[8];
  const float* b2   = (const float*)d_in[9];
  float* out = (float*)d_out;

  // workspace layout (units of float; offsets multiples of 4 -> 16B aligned)
  float* ws = (float*)d_ws;
  size_t off = 0;
  u16* xl1b = (u16*)(ws + off); off += (size_t)N_NODESC*HC/2;     // bf16 [N x 128]
  u16* xr1b = (u16*)(ws + off); off += (size_t)N_NODESC*HC/2;
  u16* xl2b = (u16*)(ws + off); off += (size_t)N_NODESC*OUT_CH/2; // bf16 [N x 64]
  u16* xr2b = (u16*)(ws + off); off += (size_t)N_NODESC*OUT_CH/2;
  u16* hb   = (u16*)(ws + off); off += (size_t)N_NODESC*HC/2;     // bf16 A for gemm2
  u16* w1lh = (u16*)(ws + off); off += IN_CH*HC/2;
  u16* w1rh = (u16*)(ws + off); off += IN_CH*HC/2;
  u16* w2lh = (u16*)(ws + off); off += HC*OUT_CH/2;
  u16* w2rh = (u16*)(ws + off); off += HC*OUT_CH/2;
  int* deg    = (int*)(ws + off); off += N_NODESC;
  int* rs     = (int*)(ws + off); off += N_NODESC;
  int* cursor = (int*)(ws + off); off += N_NODESC;
  int* bsum   = (int*)(ws + off); off += 256;
  int* csrc   = (int*)(ws + off); off += E_TOT;

  // ---- zero deg + misc (hist + weight prep) + CSR scan + fill ----
  hipMemsetAsync(deg, 0, N_NODESC*sizeof(int), stream);
  k_misc<<<NB_HIST + NB_PREP, 256, 0, stream>>>(
      ei, deg, W1l, W1r, W2l, W2r, w1lh, w1rh, w2lh, w2rh);
  k_scan_a<<<NB_SCAN, 256, 0, stream>>>(deg, rs, bsum);
  k_scan_bc<<<NB_SCAN, 256, 0, stream>>>(rs, bsum, cursor);
  k_fill<<<(E_TOT+255)/256, 256, 0, stream>>>(ei, cursor, csrc);

  // ---- layer 1 ----
  k_gemm1<<<(N_STRIPS+3)/4, 256, 0, stream>>>(x, w1lh, w1rh, xl1b, xr1b);
  k_fused1<<<(N_NODESC+3)/4, 256, 0, stream>>>(rs, deg, csrc, xl1b, xr1b, att1, b1, hb);

  // ---- layer 2 ----
  k_gemm_regB<2,4><<<(N_STRIPS+3)/4, 256, 0, stream>>>(hb, w2lh, w2rh, xl2b, xr2b);
  k_fused2<<<(N_NODESC+3)/4, 256, 0, stream>>>(rs, deg, csrc, xl2b, xr2b, att2, b2, out);
}

// Round 14
// 231.259 us; speedup vs baseline: 1.0213x; 1.0205x over previous
//
#include <hip/hip_runtime.h>
#include <hip/hip_bf16.h>
#include <math.h>

#define N_NODESC 50000
#define N_EDGESC 500000
#define E_TOT    (N_EDGESC + N_NODESC)   // 550000 (self-loops appended)
#define IN_CH 128
#define HID 32
#define HEADS 4
#define HC (HEADS*HID)    // 128
#define OUT_CH 64
#define NEG_SLOPE 0.2f
#define NB_SCAN 196        // ceil(50000/256)
#define N_STRIPS (N_NODESC/16)   // 3125 exact
#define NB_HIST 2149       // ceil(E_TOT/256)
#define NB_PREP 24
#define NB_SPLIT 6250      // ceil(N_NODESC*HC/4/256)

typedef unsigned short u16;
typedef __attribute__((ext_vector_type(8))) short short8;          // 8 bf16 (4 VGPRs)
typedef __attribute__((ext_vector_type(8))) unsigned short ushort8v;
typedef __attribute__((ext_vector_type(4))) float floatx4;         // 4 fp32 acc

// manual bf16 round-to-nearest-even
__device__ __forceinline__ u16 f2bf(float f){
  unsigned u = __float_as_uint(f);
  return (u16)((u + 0x7FFFu + ((u >> 16) & 1u)) >> 16);
}
__device__ __forceinline__ float bf2f(u16 b){ return __uint_as_float(((unsigned)b) << 16); }
// lrelu(v) = max(v, 0.2v)  (valid since 0 < slope < 1)
__device__ __forceinline__ float lrelu(float v){ return fmaxf(v, NEG_SLOPE*v); }

__device__ __forceinline__ void edge_sd(const int* __restrict__ ei, int e, int& s, int& d){
  if (e < N_EDGESC){ s = ei[e]; d = ei[N_EDGESC + e]; }
  else { s = e - N_EDGESC; d = s; }
}

// ---------------- misc: hist + weight prep + x->bf16 (deg pre-zeroed by memset) ----
// blocks 0..2148: hist; 2149..2172: weight prep; 2173..: x bf16 cast.
__global__ void k_misc(const int* __restrict__ ei, int* __restrict__ deg,
                       const float* __restrict__ X, u16* __restrict__ xhb,
                       const float* __restrict__ W1l, const float* __restrict__ W1r,
                       const float* __restrict__ W2l, const float* __restrict__ W2r,
                       u16* __restrict__ w1lh, u16* __restrict__ w1rh,
                       u16* __restrict__ w2lh, u16* __restrict__ w2rh){
  int b = blockIdx.x;
  if (b < NB_HIST){
    int e = b*256 + threadIdx.x;
    if (e < E_TOT){
      int s, d; edge_sd(ei, e, s, d);
      atomicAdd(&deg[d], 1);
    }
  } else if (b < NB_HIST + NB_PREP){
    int bb = b - NB_HIST;
    const float* W; u16 *Th; int N, base;
    if (bb < 8)      { W=W1l; Th=w1lh; N=HC;     base=bb;    }
    else if (bb < 16){ W=W1r; Th=w1rh; N=HC;     base=bb-8;  }
    else if (bb < 20){ W=W2l; Th=w2lh; N=OUT_CH; base=bb-16; }
    else             { W=W2r; Th=w2rh; N=OUT_CH; base=bb-20; }
    // packed idx = (((c*4 + t)*64) + lane)*8 + j
    // value      = W[(t*32 + (lane>>4)*8 + j)*N + c*16 + (lane&15)]
    int tid = base*256 + threadIdx.x;
    int lane = tid & 63;
    int t = (tid >> 6) & 3;
    int c = tid >> 8;
    int k0 = t*32 + (lane>>4)*8;
    int n  = c*16 + (lane&15);
    #pragma unroll
    for (int j=0;j<8;j++){
      Th[(size_t)tid*8 + j] = f2bf(W[(size_t)(k0+j)*N + n]);
    }
  } else {
    int i = (b - NB_HIST - NB_PREP)*256 + threadIdx.x;
    if (i < N_NODESC*HC/4){
      float4 v = ((const float4*)X)[i];
      ushort4 h;
      h.x = f2bf(v.x); h.y = f2bf(v.y); h.z = f2bf(v.z); h.w = f2bf(v.w);
      ((ushort4*)xhb)[i] = h;
    }
  }
}

// ---------------- CSR scan ----------------
__global__ void k_scan_a(const int* __restrict__ deg, int* __restrict__ rs,
                         int* __restrict__ bsum){
  __shared__ int sh[256];
  int i = blockIdx.x*256 + threadIdx.x;
  int v = (i < N_NODESC) ? deg[i] : 0;
  sh[threadIdx.x] = v;
  __syncthreads();
  for (int off=1; off<256; off<<=1){
    int t = (threadIdx.x >= off) ? sh[threadIdx.x-off] : 0;
    __syncthreads();
    sh[threadIdx.x] += t;
    __syncthreads();
  }
  if (i < N_NODESC) rs[i] = sh[threadIdx.x] - v;       // exclusive within block
  if (threadIdx.x == 255) bsum[blockIdx.x] = sh[255];  // block total
}

// scan of bsum (redone per block, cheap) + add + cursor init
__global__ void k_scan_bc(int* __restrict__ rs, const int* __restrict__ bsum,
                          int* __restrict__ cursor){
  __shared__ int sh[256];
  int v = (threadIdx.x < NB_SCAN) ? bsum[threadIdx.x] : 0;
  sh[threadIdx.x] = v;
  __syncthreads();
  for (int off=1; off<256; off<<=1){
    int t = (threadIdx.x >= off) ? sh[threadIdx.x-off] : 0;
    __syncthreads();
    sh[threadIdx.x] += t;
    __syncthreads();
  }
  int add = sh[blockIdx.x] - bsum[blockIdx.x];
  int i = blockIdx.x*256 + threadIdx.x;
  if (i < N_NODESC){
    int v2 = rs[i] + add;
    rs[i] = v2;
    cursor[i] = v2;
  }
}

__global__ void k_fill(const int* __restrict__ ei, int* __restrict__ cursor,
                       int* __restrict__ csrc){
  int e = blockIdx.x*blockDim.x + threadIdx.x;
  if (e >= E_TOT) return;
  int s, d; edge_sd(ei, e, s, d);
  int pos = atomicAdd(&cursor[d], 1);
  csrc[pos] = s;
}

// ---------------- register-B MFMA GEMM (bf16 A, bf16 B, bf16 outputs) -------------
// Block = 4 waves. Waves 0,1 -> A@Wl into Olb; waves 2,3 -> A@Wr into Orb.
// Each wave owns NCW column-tiles of B in VGPRs; A double-buffered in registers.
template<int NCW, int SPB>
__launch_bounds__(256, 2)
__global__ void k_gemm_regB(const u16* __restrict__ Ab,
                            const u16* __restrict__ BlT, const u16* __restrict__ BrT,
                            u16* __restrict__ Olb, u16* __restrict__ Orb){
  constexpr int NLD = 2*NCW*16;
  int wave = threadIdx.x >> 6, lane = threadIdx.x & 63;
  int m = lane & 15, quad = lane >> 4;
  bool isl = (wave < 2);
  int ctbase = (isl ? wave : wave - 2) * NCW;
  const u16* __restrict__ BT = isl ? BlT : BrT;
  u16* __restrict__ Ob = isl ? Olb : Orb;

  short8 breg[NCW][4];
  #pragma unroll
  for (int c=0;c<NCW;c++)
    #pragma unroll
    for (int t=0;t<4;t++)
      breg[c][t] = *(const short8*)(BT + ((size_t)(((ctbase+c)*4 + t)*64) + lane)*8);

  int strip0 = blockIdx.x * SPB;
  short8 ah[2][4];

  {
    const u16* p1 = Ab + (size_t)(strip0*16 + m)*128 + quad*8;
    #pragma unroll
    for (int t=0;t<4;t++) ah[0][t] = *(const short8*)(p1 + t*32);
  }

  #pragma unroll
  for (int i=0;i<SPB;i++){
    int s = strip0 + i;
    if (s >= N_STRIPS) break;
    if (i+1 < SPB && s+1 < N_STRIPS){
      const u16* p1 = Ab + (size_t)((s+1)*16 + m)*128 + quad*8;
      #pragma unroll
      for (int t=0;t<4;t++) ah[(i+1)&1][t] = *(const short8*)(p1 + t*32);
    }
    const int b = i&1;
    floatx4 acc[NCW];
    #pragma unroll
    for (int c=0;c<NCW;c++) acc[c] = (floatx4){0.f,0.f,0.f,0.f};
    #pragma unroll
    for (int t=0;t<4;t++){
      #pragma unroll
      for (int c=0;c<NCW;c++)
        acc[c] = __builtin_amdgcn_mfma_f32_16x16x32_bf16(ah[b][t], breg[c][t], acc[c], 0,0,0);
    }
    int row0 = s*16;
    #pragma unroll
    for (int c=0;c<NCW;c++)
      #pragma unroll
      for (int r=0;r<4;r++)
        Ob[(size_t)(row0 + quad*4 + r)*NLD + (ctbase+c)*16 + m] = f2bf(acc[c][r]);
  }
}

// ---------------- layer 1 fused: 4 groups x 16 lanes, shfl-broadcast indices ------
// Wave per dst. Up to 64 neighbor indices per coalesced load; per-edge index via
// __shfl. Lane l covers ch 8l..8l+7 (head = l>>2); per-head score in 2 shfl;
// cross-group combine at end. No max-subtraction (scores O(5); alpha
// shift-invariant). Output h as bf16 only (feeds gemm2 A directly).
__global__ void k_fused1(const int* __restrict__ rs, const int* __restrict__ deg,
                         const int* __restrict__ csrc, const u16* __restrict__ xlb,
                         const u16* __restrict__ xrb, const float* __restrict__ att,
                         const float* __restrict__ b1, u16* __restrict__ Hb){
  int wave = threadIdx.x >> 6;
  int lane = threadIdx.x & 63;
  int d = blockIdx.x*4 + wave;
  if (d >= N_NODESC) return;
  int g = lane >> 4;        // edge slot
  int l = lane & 15;        // channel slice: 8l..8l+7

  float xrv[8], atv[8];
  {
    ushort8v xq = *(const ushort8v*)(xrb + (size_t)d*HC + 8*l);
    #pragma unroll
    for (int j=0;j<8;j++) xrv[j] = bf2f(xq[j]);
    float4 c = *(const float4*)(att + 8*l);
    float4 e = *(const float4*)(att + 8*l + 4);
    atv[0]=c.x; atv[1]=c.y; atv[2]=c.z; atv[3]=c.w;
    atv[4]=e.x; atv[5]=e.y; atv[6]=e.z; atv[7]=e.w;
  }

  int start = rs[d], degd = deg[d];

  float acc[8];
  #pragma unroll
  for (int j=0;j<8;j++) acc[j] = 0.f;
  float den = 0.f;

  for (int base = 0; base < degd; base += 64){
    int nb = degd - base; if (nb > 64) nb = 64;
    int idx = csrc[start + base + ((lane < nb) ? lane : 0)];   // one coalesced load
    for (int i = 0; i < nb; i += 4){
      bool valid = (i + g < nb);
      int s = __shfl(idx, i + g);                 // i+g <= 63 always
      ushort8v q = *(const ushort8v*)(xlb + (size_t)s*HC + 8*l);  // 16B gather
      float xv[8];
      float sc = 0.f;
      #pragma unroll
      for (int j=0;j<8;j++){
        xv[j] = bf2f(q[j]);
        sc = fmaf(lrelu(xv[j] + xrv[j]), atv[j], sc);
      }
      sc += __shfl_xor(sc, 1);
      sc += __shfl_xor(sc, 2);          // per-head sum (4-lane span)
      float p = valid ? __expf(sc) : 0.f;
      den += p;
      #pragma unroll
      for (int j=0;j<8;j++) acc[j] = fmaf(p, xv[j], acc[j]);
    }
  }
  // cross-group combine
  #pragma unroll
  for (int j=0;j<8;j++){
    acc[j] += __shfl_xor(acc[j], 16);
    acc[j] += __shfl_xor(acc[j], 32);
  }
  den += __shfl_xor(den, 16);
  den += __shfl_xor(den, 32);

  if (g == 0){
    float bv[8];
    float4 a = *(const float4*)(b1 + 8*l);
    float4 b = *(const float4*)(b1 + 8*l + 4);
    bv[0]=a.x; bv[1]=a.y; bv[2]=a.z; bv[3]=a.w;
    bv[4]=b.x; bv[5]=b.y; bv[6]=b.z; bv[7]=b.w;
    float inv = 1.f / (den + 1e-16f);
    u16 ohv[8];
    #pragma unroll
    for (int j=0;j<8;j++){
      float o = acc[j]*inv + bv[j];
      o = (o > 0.f) ? o : (__expf(o) - 1.f);
      ohv[j] = f2bf(o);
    }
    ushort4 h0 = {ohv[0],ohv[1],ohv[2],ohv[3]}, h1 = {ohv[4],ohv[5],ohv[6],ohv[7]};
    *(ushort4*)(Hb + (size_t)d*HC + 8*l)     = h0;
    *(ushort4*)(Hb + (size_t)d*HC + 8*l + 4) = h1;
  }
}

// ---------------- layer 2 fused: 8 groups x 8 lanes, shfl-broadcast indices -------
// Lane l covers ch 8l..8l+7 (16B gather); score over 8 lanes (3 shfl); heads=1.
__global__ void k_fused2(const int* __restrict__ rs, const int* __restrict__ deg,
                         const int* __restrict__ csrc, const u16* __restrict__ xlb,
                         const u16* __restrict__ xrb, const float* __restrict__ att,
                         const float* __restrict__ b2, float* __restrict__ out){
  int wave = threadIdx.x >> 6;
  int lane = threadIdx.x & 63;
  int d = blockIdx.x*4 + wave;
  if (d >= N_NODESC) return;
  int g = lane >> 3;        // 8 edge slots
  int l = lane & 7;         // channels 8l..8l+7

  float xrv[8], atv[8];
  {
    ushort8v xq = *(const ushort8v*)(xrb + (size_t)d*OUT_CH + 8*l);
    #pragma unroll
    for (int j=0;j<8;j++) xrv[j] = bf2f(xq[j]);
    float4 c = *(const float4*)(att + 8*l);
    float4 e = *(const float4*)(att + 8*l + 4);
    atv[0]=c.x; atv[1]=c.y; atv[2]=c.z; atv[3]=c.w;
    atv[4]=e.x; atv[5]=e.y; atv[6]=e.z; atv[7]=e.w;
  }

  int start = rs[d], degd = deg[d];

  float acc[8];
  #pragma unroll
  for (int j=0;j<8;j++) acc[j] = 0.f;
  float den = 0.f;

  for (int base = 0; base < degd; base += 64){
    int nb = degd - base; if (nb > 64) nb = 64;
    int idx = csrc[start + base + ((lane < nb) ? lane : 0)];
    for (int i = 0; i < nb; i += 8){
      bool valid = (i + g < nb);
      int s = __shfl(idx, i + g);                 // i+g <= 63 always
      ushort8v q = *(const ushort8v*)(xlb + (size_t)s*OUT_CH + 8*l);  // 16B gather
      float xv[8];
      float sc = 0.f;
      #pragma unroll
      for (int j=0;j<8;j++){
        xv[j] = bf2f(q[j]);
        sc = fmaf(lrelu(xv[j] + xrv[j]), atv[j], sc);
      }
      sc += __shfl_xor(sc, 1);
      sc += __shfl_xor(sc, 2);
      sc += __shfl_xor(sc, 4);          // full 64-ch sum (8-lane span)
      float p = valid ? __expf(sc) : 0.f;
      den += p;
      #pragma unroll
      for (int j=0;j<8;j++) acc[j] = fmaf(p, xv[j], acc[j]);
    }
  }
  // cross-group combine (8 groups)
  #pragma unroll
  for (int j=0;j<8;j++){
    acc[j] += __shfl_xor(acc[j], 8);
    acc[j] += __shfl_xor(acc[j], 16);
    acc[j] += __shfl_xor(acc[j], 32);
  }
  den += __shfl_xor(den, 8);
  den += __shfl_xor(den, 16);
  den += __shfl_xor(den, 32);

  if (g == 0){
    float bv[8];
    float4 a = *(const float4*)(b2 + 8*l);
    float4 b = *(const float4*)(b2 + 8*l + 4);
    bv[0]=a.x; bv[1]=a.y; bv[2]=a.z; bv[3]=a.w;
    bv[4]=b.x; bv[5]=b.y; bv[6]=b.z; bv[7]=b.w;
    float inv = 1.f / (den + 1e-16f);
    float4 o0, o1;
    o0.x = acc[0]*inv + bv[0]; o0.y = acc[1]*inv + bv[1];
    o0.z = acc[2]*inv + bv[2]; o0.w = acc[3]*inv + bv[3];
    o1.x = acc[4]*inv + bv[4]; o1.y = acc[5]*inv + bv[5];
    o1.z = acc[6]*inv + bv[6]; o1.w = acc[7]*inv + bv[7];
    *(float4*)(out + (size_t)d*OUT_CH + 8*l)     = o0;
    *(float4*)(out + (size_t)d*OUT_CH + 8*l + 4) = o1;
  }
}

extern "C" void kernel_launch(void* const* d_in, const int* in_sizes, int n_in,
                              void* d_out, int out_size, void* d_ws, size_t ws_size,
                              hipStream_t stream) {
  const float* x    = (const float*)d_in[0];
  const int*   ei   = (const int*)d_in[1];
  const float* W1l  = (const float*)d_in[2];
  const float* W1r  = (const float*)d_in[3];
  const float* att1 = (const float*)d_in[4];
  const float* b1   = (const float*)d_in[5];
  const float* W2l  = (const float*)d_in[6];
  const float* W2r  = (const float*)d_in[7];
  const float* att2 = (const float*)d_in[8];
  const float* b2   = (const float*)d_in[9];
  float* out = (float*)d_out;

  // workspace layout (units of float; offsets multiples of 4 -> 16B aligned)
  float* ws = (float*)d_ws;
  size_t off = 0;
  u16* xl1b = (u16*)(ws + off); off += (size_t)N_NODESC*HC/2;     // bf16 [N x 128]
  u16* xr1b = (u16*)(ws + off); off += (size_t)N_NODESC*HC/2;
  u16* xl2b = (u16*)(ws + off); off += (size_t)N_NODESC*OUT_CH/2; // bf16 [N x 64]
  u16* xr2b = (u16*)(ws + off); off += (size_t)N_NODESC*OUT_CH/2;
  u16* xhb  = (u16*)(ws + off); off += (size_t)N_NODESC*HC/2;     // bf16 A for gemm1
  u16* hb   = (u16*)(ws + off); off += (size_t)N_NODESC*HC/2;     // bf16 A for gemm2
  u16* w1lh = (u16*)(ws + off); off += IN_CH*HC/2;
  u16* w1rh = (u16*)(ws + off); off += IN_CH*HC/2;
  u16* w2lh = (u16*)(ws + off); off += HC*OUT_CH/2;
  u16* w2rh = (u16*)(ws + off); off += HC*OUT_CH/2;
  int* deg    = (int*)(ws + off); off += N_NODESC;
  int* rs     = (int*)(ws + off); off += N_NODESC;
  int* cursor = (int*)(ws + off); off += N_NODESC;
  int* bsum   = (int*)(ws + off); off += 256;
  int* csrc   = (int*)(ws + off); off += E_TOT;

  // ---- zero deg (async memset) + misc (hist + prep + cast) + CSR scan/fill ----
  hipMemsetAsync(deg, 0, N_NODESC*sizeof(int), stream);
  k_misc<<<NB_HIST + NB_PREP + NB_SPLIT, 256, 0, stream>>>(
      ei, deg, x, xhb, W1l, W1r, W2l, W2r, w1lh, w1rh, w2lh, w2rh);
  k_scan_a<<<NB_SCAN, 256, 0, stream>>>(deg, rs, bsum);
  k_scan_bc<<<NB_SCAN, 256, 0, stream>>>(rs, bsum, cursor);
  k_fill<<<(E_TOT+255)/256, 256, 0, stream>>>(ei, cursor, csrc);

  const int NB_G = (N_STRIPS + 3)/4;   // SPB=4
  // ---- layer 1 ----
  k_gemm_regB<4,4><<<NB_G, 256, 0, stream>>>(xhb, w1lh, w1rh, xl1b, xr1b);
  k_fused1<<<(N_NODESC+3)/4, 256, 0, stream>>>(rs, deg, csrc, xl1b, xr1b, att1, b1, hb);

  // ---- layer 2 ----
  k_gemm_regB<2,4><<<NB_G, 256, 0, stream>>>(hb, w2lh, w2rh, xl2b, xr2b);
  k_fused2<<<(N_NODESC+3)/4, 256, 0, stream>>>(rs, deg, csrc, xl2b, xr2b, att2, b2, out);
}